// Round 1
// baseline (163.112 us; speedup 1.0000x reference)
//
#include <hip/hip_runtime.h>
#include <math.h>

// SoftGlidingBoxes: for each (b, ch=c*8+l) 256x256 image and scale s=1..8,
// sum over valid positions of the s x s sliding-window max, then relu(.)+1.
// x: [16, 256, 256, 3, 8] fp32 -> out: [16, 3, 8, 8] fp32.
//
// Round-3 design: bottom-to-top register DP using
//   M_s[i][j] = max of four (s-1)-windows at (i,j),(i,j+1),(i+1,j),(i+1,j+1)
// Each thread owns (ch, 8-col strip); prev-row M_1..M_7 live in 56 VGPRs.
// Each input row is read from LDS exactly once (8 x b32, conflict-free via
// swizzled padding). One barrier per row (double-buffered row staging with
// perfectly coalesced float4 global loads).
//
// Round-3 deltas vs round-2 (162.5 us):
//  * nbP[] cache: nbOld for scale s == previous row's nbNew at the same
//    scale, so keep it in a register instead of a second ds_bpermute.
//    14 -> 7 shuffles per thread-row, and shortens the shfl->max dep chain.
//  * 4-way max written as a left chain so it folds to v_max3_f32 + v_max_f32
//    (2 VALU) instead of a 3-op tree. Exact arithmetic, absmax unchanged.

namespace {
constexpr int Bn = 16, Hn = 256, Wn = 256, CHn = 24, Sn = 8;
constexpr int IT = 16;               // output rows per band
constexpr int NBANDS = Hn / IT;      // 16
constexpr int NSTRIP = 32;           // strips of 8 cols -> full 256-col width
constexpr int BDIM = CHn * NSTRIP;   // 768 threads = 12 waves
constexpr int ROWF = Wn * CHn;       // 6144 floats per image row
// LDS row layout: addr(c,ch) = c*25 + ch + (c>>3)*5  (max 6553)
// -> compute-read banks = (13*strip + ch) % 32 : full permutation, conflict-free
constexpr int LROW = 6560;
constexpr int OUT_N = Bn * CHn * Sn; // 3072
}

__device__ __forceinline__ int lds_addr(int c, int ch) {
  return c * 25 + ch + (c >> 3) * 5;
}

__global__ __launch_bounds__(BDIM, 3) void sgb_main(const float* __restrict__ x,
                                                    float* __restrict__ accum) {
  __shared__ float buf[2][LROW];

  const int band = blockIdx.x;
  const int b    = blockIdx.y;
  const int i0   = band * IT;
  const int tid  = threadIdx.x;
  const int ch    = tid >> 5;      // 0..23   (tid = ch*32 + strip)
  const int strip = tid & 31;      // 0..31, cols [strip*8, strip*8+8)
  const int rbase = strip * 205 + ch;          // lds_addr(strip*8, ch)
  // writer role: this thread stages row elements e = 8*tid .. 8*tid+7,
  // which are 8 consecutive ch of column cw = tid/3 -> contiguous in LDS.
  const int wbase = lds_addr(tid / 3, (tid % 3) * 8);

  float P[7][8];                   // prev-row M_1..M_7 for own 8 cols
  float nbP[7];                    // prev-row M_1..M_7 at neighbor's col 0
#pragma unroll
  for (int s = 0; s < 7; ++s) {
    nbP[s] = -INFINITY;
#pragma unroll
    for (int j = 0; j < 8; ++j) P[s][j] = -INFINITY;
  }

  float acc[Sn];
#pragma unroll
  for (int s = 0; s < Sn; ++s) acc[s] = 0.f;

  const float* img = x + (long)(b * Hn) * ROWF;
  const int rhi = i0 + IT + 6;     // topmost staged row (may exceed H-1)

  // Prologue: stage row rhi into buf[0].
  if (rhi < Hn) {
    const float* src = img + rhi * ROWF + tid * 8;
    float4 v0 = reinterpret_cast<const float4*>(src)[0];
    float4 v1 = reinterpret_cast<const float4*>(src)[1];
    float* d = &buf[0][wbase];
    d[0] = v0.x; d[1] = v0.y; d[2] = v0.z; d[3] = v0.w;
    d[4] = v1.x; d[5] = v1.y; d[6] = v1.z; d[7] = v1.w;
  }

  for (int idx = 0; idx < IT + 7; ++idx) {
    const int r  = rhi - idx;      // current row (descending)
    const int pb = idx & 1;
    __syncthreads();               // staged writes of row r now visible

    // Issue next row's global loads early; LDS-write them after compute.
    const bool do_stage = (idx < IT + 6) && (r - 1 < Hn);
    float4 v0, v1;
    if (do_stage) {
      const float* src = img + (r - 1) * ROWF + tid * 8;
      v0 = reinterpret_cast<const float4*>(src)[0];
      v1 = reinterpret_cast<const float4*>(src)[1];
    }

    // cp = M_1[r] = x[r] at own 8 cols (LDS read, conflict-free).
    float cp[8];
    if (r < Hn) {
      const float* rb = &buf[pb][rbase];
#pragma unroll
      for (int k = 0; k < 8; ++k) cp[k] = rb[25 * k];
    } else {
#pragma unroll
      for (int k = 0; k < 8; ++k) cp[k] = -INFINITY;
    }

    const bool outrow = (r < i0 + IT);   // r >= i0 always holds
    if (outrow) {  // s=1: every col 0..255 is a valid window start
      acc[0] += ((cp[0] + cp[1]) + (cp[2] + cp[3])) +
                ((cp[4] + cp[5]) + (cp[6] + cp[7]));
    }

#pragma unroll
    for (int s = 2; s <= Sn; ++s) {
      // col-8 halo = right neighbor's col 0 (strip+1 == lane+1).
      // strip 31's pulls are garbage but land only in windows with
      // j+s>8, i.e. exactly the invalid (c+s>256) ones -> masked below.
      // nbOld (prev row M_{s-1}[col 8]) == previous row's nbNew at this
      // scale: P[s-2][0] was set to that row's cp[0], so shfl(P[s-2][0])
      // == that row's shfl(cp[0]). Cached in nbP -> one shuffle per scale.
      float nbNew = __shfl_down(cp[0], 1);        // new M_{s-1}[col 8]
      float nbOld = nbP[s - 2];                   // prev-row M_{s-1}[col 8]
      float cc[8];
#pragma unroll
      for (int j = 0; j < 7; ++j)
        cc[j] = fmaxf(fmaxf(fmaxf(cp[j], cp[j + 1]), P[s - 2][j]),
                      P[s - 2][j + 1]);           // v_max3 + v_max
      cc[7] = fmaxf(fmaxf(fmaxf(cp[7], nbNew), P[s - 2][7]), nbOld);

      if (outrow && (r + s <= Hn)) {
        float lo = 0.f, hi = 0.f;   // hi = windows needing cols past strip end
#pragma unroll
        for (int j = 0; j < 8; ++j) {
          if (j <= 8 - s) lo += cc[j]; else hi += cc[j];
        }
        acc[s - 1] += lo + (strip == NSTRIP - 1 ? 0.f : hi);
      }
      nbP[s - 2] = nbNew;
#pragma unroll
      for (int j = 0; j < 8; ++j) { P[s - 2][j] = cp[j]; cp[j] = cc[j]; }
    }

    if (do_stage) {
      float* d = &buf[pb ^ 1][wbase];
      d[0] = v0.x; d[1] = v0.y; d[2] = v0.z; d[3] = v0.w;
      d[4] = v1.x; d[5] = v1.y; d[6] = v1.z; d[7] = v1.w;
    }
  }

  // Reduce 32 strips per ch (lanes [0,31] / [32,63] share ch) and accumulate.
#pragma unroll
  for (int s = 0; s < Sn; ++s) {
    float v = acc[s];
    v += __shfl_xor(v, 16);
    v += __shfl_xor(v, 8);
    v += __shfl_xor(v, 4);
    v += __shfl_xor(v, 2);
    v += __shfl_xor(v, 1);
    if (strip == 0) atomicAdd(&accum[(b * CHn + ch) * Sn + s], v);
  }
}

__global__ void sgb_finalize(float* __restrict__ out) {
  const int i = blockIdx.x * blockDim.x + threadIdx.x;
  if (i < OUT_N) out[i] = fmaxf(out[i], 0.f) + 1.f;
}

extern "C" void kernel_launch(void* const* d_in, const int* in_sizes, int n_in,
                              void* d_out, int out_size, void* d_ws, size_t ws_size,
                              hipStream_t stream) {
  (void)in_sizes; (void)n_in; (void)d_ws; (void)ws_size; (void)out_size;
  const float* x = (const float*)d_in[0];
  float* out = (float*)d_out;

  hipMemsetAsync(out, 0, OUT_N * sizeof(float), stream);
  dim3 grid(NBANDS, Bn);               // 16 x 16 = 256 blocks of 768 threads
  sgb_main<<<grid, BDIM, 0, stream>>>(x, out);
  sgb_finalize<<<(OUT_N + 255) / 256, 256, 0, stream>>>(out);
}